// Round 1
// baseline (2496.689 us; speedup 1.0000x reference)
//
#include <hip/hip_runtime.h>
#include <stdint.h>
#include <math.h>

// Problem constants
constexpr int Dd  = 64;
constexpr int Nn  = 32768;          // B*H*W = 32*32*32
constexpr int Kk  = 1024;

// d_out layout (floats)
constexpr int OUT0_N   = 32 * 64 * 1024;       // 2097152 (z_st, [B,D,H,W])
constexpr int OUT_LOSS = OUT0_N;               // 2097152
constexpr int OUT_PERP = OUT0_N + 1;           // 2097153
constexpr int OUT_ENC  = OUT0_N + 2;           // 2097154
constexpr int ENC_N    = Nn * Kk;              // 33554432
// candidate scratch: u64 cand[256 rowgroups][8 codegroups][128 rows] = 2MB,
// placed at the TAIL of the encodings region; merge_kernel consumes it before
// enc_kernel overwrites it. byte offset divisible by 8.
constexpr long long CAND_FLOAT_OFF = (long long)OUT_ENC + ENC_N - 2LL * 256 * 8 * 128; // 35127298

// d_ws layout (bytes)
constexpr size_t WS_LOSS = 0;                   // double
constexpr size_t WS_CNT  = 64;                  // uint32[1024]
constexpr size_t WS_BN   = WS_CNT + 4096;       // float[1024]
constexpr size_t WS_AN   = WS_BN + 4096;        // float[32768]
constexpr size_t WS_IDX  = WS_AN + 131072;      // uint32[32768]

// ---------------------------------------------------------------------------
// Kernel 1: row norms A[n] and code norms B[k], replicating numpy pairwise sum
// for n=64: t[i]=fl(x*x); r[j] = sum of t[j],t[j+8],...,t[j+56] sequentially;
// result = ((r0+r1)+(r2+r3))+((r4+r5)+(r6+r7)). Contraction OFF so t=x*x is
// rounded separately (no fma fusion into the adds).
// ---------------------------------------------------------------------------
__global__ void norms_kernel(const float* __restrict__ z_e,
                             const float* __restrict__ emb,
                             float* __restrict__ An, float* __restrict__ Bn) {
#pragma clang fp contract(off)
    int t = blockIdx.x * blockDim.x + threadIdx.x;
    if (t < Nn) {
        int b = t >> 10, hw = t & 1023;
        const float* p = z_e + (size_t)b * 65536 + hw;
        float tt[64];
#pragma unroll
        for (int d = 0; d < 64; ++d) { float v = p[(size_t)d * 1024]; tt[d] = v * v; }
        float r[8];
#pragma unroll
        for (int j = 0; j < 8; ++j) r[j] = tt[j];
#pragma unroll
        for (int i = 8; i < 64; i += 8)
#pragma unroll
            for (int j = 0; j < 8; ++j) r[j] += tt[i + j];
        An[t] = ((r[0] + r[1]) + (r[2] + r[3])) + ((r[4] + r[5]) + (r[6] + r[7]));
    } else if (t < Nn + Kk) {
        int k = t - Nn;
        const float* p = emb + (size_t)k * 64;
        float tt[64];
#pragma unroll
        for (int d = 0; d < 64; ++d) { float v = p[d]; tt[d] = v * v; }
        float r[8];
#pragma unroll
        for (int j = 0; j < 8; ++j) r[j] = tt[j];
#pragma unroll
        for (int i = 8; i < 64; i += 8)
#pragma unroll
            for (int j = 0; j < 8; ++j) r[j] += tt[i + j];
        Bn[k] = ((r[0] + r[1]) + (r[2] + r[3])) + ((r[4] + r[5]) + (r[6] + r[7]));
    }
}

// ---------------------------------------------------------------------------
// Kernel 2: tiled distance + per-block argmin.
// Grid: 2048 blocks = 256 rowgroups x 8 codegroups. Block: 256 threads (16x16).
// Tile 128 rows x 128 codes; per-thread 8x8; D=64 fully staged in LDS.
// C accumulated as a sequential fmaf chain over d=0..63 (matches OpenBLAS
// sgemm k-order). dist = fl(fl(A+B) - 2C). Tie-break to lowest code via
// packed (sortable_bits<<32)|code u64 min.
// ---------------------------------------------------------------------------
__device__ __forceinline__ uint32_t fsort(float f) {
    uint32_t b = __float_as_uint(f);
    return (b & 0x80000000u) ? ~b : (b | 0x80000000u);
}

__global__ __launch_bounds__(256, 2)
void dist_kernel(const float* __restrict__ z_e, const float* __restrict__ emb,
                 const float* __restrict__ An, const float* __restrict__ Bn,
                 unsigned long long* __restrict__ cand) {
    __shared__ float xs[128 * 68];   // [row][d], stride 68 floats (272B, 16B aligned)
    __shared__ float es[128 * 68];   // [code][d]
    const int tid = threadIdx.x;
    const int rg = blockIdx.x >> 3, cg = blockIdx.x & 7;
    const int n0 = rg * 128;
    const int b = n0 >> 10, hw0 = n0 & 1023;
    const float* zb = z_e + (size_t)b * 65536 + hw0;

    // stage x-tile: 4 coalesced d-slices per float4 LDS write
    {
        int hwi = tid & 127;
        int d4g = tid >> 7;   // 0..1
#pragma unroll
        for (int it = 0; it < 8; ++it) {
            int dbase = (d4g + it * 2) * 4;
            float4 v;
            v.x = zb[(size_t)(dbase + 0) * 1024 + hwi];
            v.y = zb[(size_t)(dbase + 1) * 1024 + hwi];
            v.z = zb[(size_t)(dbase + 2) * 1024 + hwi];
            v.w = zb[(size_t)(dbase + 3) * 1024 + hwi];
            *(float4*)&xs[hwi * 68 + dbase] = v;
        }
    }
    // stage e-tile: contiguous 32KB, coalesced float4
    {
        const float4* ep = (const float4*)(emb + (size_t)cg * 128 * 64);
#pragma unroll
        for (int it = 0; it < 8; ++it) {
            int j = tid + it * 256;      // 0..2047
            float4 v = ep[j];
            int c = j >> 4, d4 = j & 15;
            *(float4*)&es[c * 68 + d4 * 4] = v;
        }
    }
    __syncthreads();

    const int tx = tid & 15, ty = tid >> 4;
    float acc[8][8];
#pragma unroll
    for (int i = 0; i < 8; ++i)
#pragma unroll
        for (int j = 0; j < 8; ++j) acc[i][j] = 0.0f;

#pragma unroll
    for (int d4 = 0; d4 < 16; ++d4) {
        float4 xv[8], ev[8];
#pragma unroll
        for (int i = 0; i < 8; ++i) xv[i] = *(const float4*)&xs[(ty + 16 * i) * 68 + d4 * 4];
#pragma unroll
        for (int j = 0; j < 8; ++j) ev[j] = *(const float4*)&es[(tx + 16 * j) * 68 + d4 * 4];
#pragma unroll
        for (int i = 0; i < 8; ++i)
#pragma unroll
            for (int j = 0; j < 8; ++j) {
                float a = acc[i][j];
                a = __builtin_fmaf(xv[i].x, ev[j].x, a);
                a = __builtin_fmaf(xv[i].y, ev[j].y, a);
                a = __builtin_fmaf(xv[i].z, ev[j].z, a);
                a = __builtin_fmaf(xv[i].w, ev[j].w, a);
                acc[i][j] = a;
            }
    }

    // epilogue: dist + per-row argmin over this block's 128 codes
    float Ar[8], Bc[8];
#pragma unroll
    for (int i = 0; i < 8; ++i) Ar[i] = An[n0 + ty + 16 * i];
#pragma unroll
    for (int j = 0; j < 8; ++j) Bc[j] = Bn[cg * 128 + tx + 16 * j];

    const size_t base = (size_t)blockIdx.x * 128;
#pragma unroll
    for (int i = 0; i < 8; ++i) {
        unsigned long long best = ~0ULL;
#pragma unroll
        for (int j = 0; j < 8; ++j) {
            float s = Ar[i] + Bc[j];                 // fl(A+B)
            float dist = s - 2.0f * acc[i][j];       // fl(s - 2C) (2C exact)
            unsigned long long key = ((unsigned long long)fsort(dist) << 32)
                                   | (unsigned)(cg * 128 + tx + 16 * j);
            best = (key < best) ? key : best;
        }
        // reduce across the 16 tx lanes sharing this row (lane bits 0..3)
#pragma unroll
        for (int m = 1; m < 16; m <<= 1) {
            unsigned long long o = __shfl_xor(best, m, 64);
            best = (o < best) ? o : best;
        }
        if (tx == 0) cand[base + ty + 16 * i] = best;
    }
}

// ---------------------------------------------------------------------------
// Kernel 3: merge candidates -> idx; write z_st (= z + fl(z_q - z)); counts;
// fp64 loss partial sum.
// ---------------------------------------------------------------------------
__global__ void merge_kernel(const float* __restrict__ z_e,
                             const float* __restrict__ emb,
                             const unsigned long long* __restrict__ cand,
                             float* __restrict__ out0,
                             uint32_t* __restrict__ idx,
                             uint32_t* __restrict__ counts,
                             double* __restrict__ loss_sum) {
    int n = blockIdx.x * blockDim.x + threadIdx.x;   // 128 blocks * 256
    int rg = n >> 7, r = n & 127;
    unsigned long long best = ~0ULL;
#pragma unroll
    for (int cg = 0; cg < 8; ++cg) {
        unsigned long long k = cand[((size_t)rg * 8 + cg) * 128 + r];
        best = (k < best) ? k : best;
    }
    uint32_t code = (uint32_t)best;
    idx[n] = code;
    atomicAdd(&counts[code], 1u);

    int b = n >> 10, hw = n & 1023;
    const float* zp = z_e + (size_t)b * 65536 + hw;
    float*       op = out0 + (size_t)b * 65536 + hw;
    const float* ep = emb + (size_t)code * 64;
    double ls = 0.0;
#pragma unroll
    for (int d = 0; d < 64; ++d) {
        float z  = zp[(size_t)d * 1024];
        float zq = ep[d];
        float t  = zq - z;               // fl(z_q - z), as in np
        op[(size_t)d * 1024] = z + t;    // straight-through value
        ls += (double)t * (double)t;
    }
#pragma unroll
    for (int m = 32; m >= 1; m >>= 1) ls += __shfl_down(ls, m, 64);
    if ((threadIdx.x & 63) == 0) atomicAdd(loss_sum, ls);
}

// ---------------------------------------------------------------------------
// Kernel 4: scalars (loss, perplexity) in fp64 (2% thresholds, big slack)
// ---------------------------------------------------------------------------
__global__ void scalar_kernel(const uint32_t* __restrict__ counts,
                              const double* __restrict__ loss_sum,
                              float* __restrict__ out) {
    __shared__ double red[4];
    int t = threadIdx.x;   // 256
    double h = 0.0;
    for (int i = t; i < Kk; i += 256) {
        double p = (double)counts[i] * (1.0 / 32768.0);
        h += p * log(p + 1e-10);
    }
#pragma unroll
    for (int m = 32; m >= 1; m >>= 1) h += __shfl_down(h, m, 64);
    if ((t & 63) == 0) red[t >> 6] = h;
    __syncthreads();
    if (t == 0) {
        double H = red[0] + red[1] + red[2] + red[3];
        out[OUT_PERP] = (float)exp(-H);
        float m32 = (float)(loss_sum[0] * (1.0 / 2097152.0));
        out[OUT_LOSS] = m32 + 0.25f * m32;   // q + 0.25*e, q==e numerically
    }
}

// ---------------------------------------------------------------------------
// Kernel 5: one-hot encodings, float4 stores (writes the whole 134MB region,
// including the candidate scratch at its tail — consumed already).
// ---------------------------------------------------------------------------
__global__ void enc_kernel(const uint32_t* __restrict__ idx,
                           float* __restrict__ enc) {
    int t = threadIdx.x;     // 256; grid 8192
#pragma unroll
    for (int i = 0; i < 4; ++i) {
        int row = blockIdx.x + i * 8192;
        uint32_t code = idx[row];
        float4 v;
        uint32_t c0 = (uint32_t)(t * 4);
        v.x = (code == c0 + 0u) ? 1.0f : 0.0f;
        v.y = (code == c0 + 1u) ? 1.0f : 0.0f;
        v.z = (code == c0 + 2u) ? 1.0f : 0.0f;
        v.w = (code == c0 + 3u) ? 1.0f : 0.0f;
        ((float4*)enc)[(size_t)row * 256 + t] = v;
    }
}

extern "C" void kernel_launch(void* const* d_in, const int* in_sizes, int n_in,
                              void* d_out, int out_size, void* d_ws, size_t ws_size,
                              hipStream_t stream) {
    const float* z_e = (const float*)d_in[0];
    const float* emb = (const float*)d_in[1];
    float* out = (float*)d_out;
    char* ws = (char*)d_ws;

    double*   loss_sum = (double*)(ws + WS_LOSS);
    uint32_t* counts   = (uint32_t*)(ws + WS_CNT);
    float*    Bn       = (float*)(ws + WS_BN);
    float*    An       = (float*)(ws + WS_AN);
    uint32_t* idx      = (uint32_t*)(ws + WS_IDX);
    unsigned long long* cand = (unsigned long long*)(out + CAND_FLOAT_OFF);

    // zero loss accumulator + counts (ws is poisoned 0xAA before every call)
    hipMemsetAsync(ws, 0, WS_CNT + 4096, stream);

    norms_kernel<<<(Nn + Kk) / 256, 256, 0, stream>>>(z_e, emb, An, Bn);
    dist_kernel<<<2048, 256, 0, stream>>>(z_e, emb, An, Bn, cand);
    merge_kernel<<<Nn / 256, 256, 0, stream>>>(z_e, emb, cand, out, idx, counts, loss_sum);
    scalar_kernel<<<1, 256, 0, stream>>>(counts, loss_sum, out);
    enc_kernel<<<8192, 256, 0, stream>>>(idx, out + OUT_ENC);
}

// Round 2
// 242.284 us; speedup vs baseline: 10.3048x; 10.3048x over previous
//
#include <hip/hip_runtime.h>
#include <stdint.h>
#include <math.h>

// Problem constants
constexpr int Dd  = 64;
constexpr int Nn  = 32768;          // B*H*W = 32*32*32
constexpr int Kk  = 1024;

// d_out layout (floats)
constexpr int OUT0_N   = 32 * 64 * 1024;       // 2097152 (z_st, [B,D,H,W])
constexpr int OUT_LOSS = OUT0_N;               // 2097152
constexpr int OUT_PERP = OUT0_N + 1;           // 2097153
constexpr int OUT_ENC  = OUT0_N + 2;           // 2097154
constexpr int ENC_N    = Nn * Kk;              // 33554432
// candidate scratch: u64 cand[256 rowgroups][8 codegroups][128 rows] = 2MB,
// placed at the TAIL of the encodings region; merge_kernel consumes it before
// enc_kernel overwrites it. byte offset divisible by 8.
constexpr long long CAND_FLOAT_OFF = (long long)OUT_ENC + ENC_N - 2LL * 256 * 8 * 128; // 35127298

// d_ws layout (bytes)
constexpr size_t WS_LOSS = 0;                   // double
constexpr size_t WS_CNT  = 64;                  // uint32[1024]
constexpr size_t WS_BN   = WS_CNT + 4096;       // float[1024]
constexpr size_t WS_AN   = WS_BN + 4096;        // float[32768]
constexpr size_t WS_IDX  = WS_AN + 131072;      // uint32[32768]

// ---------------------------------------------------------------------------
// Kernel 1: row norms A[n] and code norms B[k], replicating numpy pairwise sum
// for n=64 (8 stride-8 accumulators, pairwise combine). Contraction OFF.
// ---------------------------------------------------------------------------
__global__ void norms_kernel(const float* __restrict__ z_e,
                             const float* __restrict__ emb,
                             float* __restrict__ An, float* __restrict__ Bn) {
#pragma clang fp contract(off)
    int t = blockIdx.x * blockDim.x + threadIdx.x;
    if (t < Nn) {
        int b = t >> 10, hw = t & 1023;
        const float* p = z_e + (size_t)b * 65536 + hw;
        float tt[64];
#pragma unroll
        for (int d = 0; d < 64; ++d) { float v = p[(size_t)d * 1024]; tt[d] = v * v; }
        float r[8];
#pragma unroll
        for (int j = 0; j < 8; ++j) r[j] = tt[j];
#pragma unroll
        for (int i = 8; i < 64; i += 8)
#pragma unroll
            for (int j = 0; j < 8; ++j) r[j] += tt[i + j];
        An[t] = ((r[0] + r[1]) + (r[2] + r[3])) + ((r[4] + r[5]) + (r[6] + r[7]));
    } else if (t < Nn + Kk) {
        int k = t - Nn;
        const float* p = emb + (size_t)k * 64;
        float tt[64];
#pragma unroll
        for (int d = 0; d < 64; ++d) { float v = p[d]; tt[d] = v * v; }
        float r[8];
#pragma unroll
        for (int j = 0; j < 8; ++j) r[j] = tt[j];
#pragma unroll
        for (int i = 8; i < 64; i += 8)
#pragma unroll
            for (int j = 0; j < 8; ++j) r[j] += tt[i + j];
        Bn[k] = ((r[0] + r[1]) + (r[2] + r[3])) + ((r[4] + r[5]) + (r[6] + r[7]));
    }
}

// ---------------------------------------------------------------------------
// Kernel 2: tiled distance + per-block argmin.
// Grid: 2048 blocks = 256 rowgroups x 8 codegroups. Block: 256 threads (16x16).
// Tile 128 rows x 128 codes; per-thread 8x8; D=64 fully staged in LDS.
// d4 loop is unroll-1: full unroll (R1) hoisted 256 float4 LDS loads, blew
// past the 256-VGPR cap and spilled acc[8][8] to scratch -> 4.9 GB HBM
// traffic, 2.3 ms. One iteration already has 16 independent b128 loads (ILP).
// ---------------------------------------------------------------------------
__device__ __forceinline__ uint32_t fsort(float f) {
    uint32_t b = __float_as_uint(f);
    return (b & 0x80000000u) ? ~b : (b | 0x80000000u);
}

__global__ __launch_bounds__(256, 2)
void dist_kernel(const float* __restrict__ z_e, const float* __restrict__ emb,
                 const float* __restrict__ An, const float* __restrict__ Bn,
                 unsigned long long* __restrict__ cand) {
    __shared__ float xs[128 * 68];   // [row][d], stride 68 floats
    __shared__ float es[128 * 68];   // [code][d]
    const int tid = threadIdx.x;
    const int rg = blockIdx.x >> 3, cg = blockIdx.x & 7;
    const int n0 = rg * 128;
    const int b = n0 >> 10, hw0 = n0 & 1023;
    const float* zb = z_e + (size_t)b * 65536 + hw0;

    // stage x-tile: 4 coalesced d-slices per float4 LDS write
    {
        int hwi = tid & 127;
        int d4g = tid >> 7;   // 0..1
#pragma unroll
        for (int it = 0; it < 8; ++it) {
            int dbase = (d4g + it * 2) * 4;
            float4 v;
            v.x = zb[(size_t)(dbase + 0) * 1024 + hwi];
            v.y = zb[(size_t)(dbase + 1) * 1024 + hwi];
            v.z = zb[(size_t)(dbase + 2) * 1024 + hwi];
            v.w = zb[(size_t)(dbase + 3) * 1024 + hwi];
            *(float4*)&xs[hwi * 68 + dbase] = v;
        }
    }
    // stage e-tile: contiguous 32KB, coalesced float4
    {
        const float4* ep = (const float4*)(emb + (size_t)cg * 128 * 64);
#pragma unroll
        for (int it = 0; it < 8; ++it) {
            int j = tid + it * 256;      // 0..2047
            float4 v = ep[j];
            int c = j >> 4, d4 = j & 15;
            *(float4*)&es[c * 68 + d4 * 4] = v;
        }
    }
    __syncthreads();

    const int tx = tid & 15, ty = tid >> 4;
    float acc[8][8];
#pragma unroll
    for (int i = 0; i < 8; ++i)
#pragma unroll
        for (int j = 0; j < 8; ++j) acc[i][j] = 0.0f;

#pragma unroll 1
    for (int d4 = 0; d4 < 16; ++d4) {
        float4 xv[8], ev[8];
#pragma unroll
        for (int i = 0; i < 8; ++i) xv[i] = *(const float4*)&xs[(ty + 16 * i) * 68 + d4 * 4];
#pragma unroll
        for (int j = 0; j < 8; ++j) ev[j] = *(const float4*)&es[(tx + 16 * j) * 68 + d4 * 4];
#pragma unroll
        for (int i = 0; i < 8; ++i)
#pragma unroll
            for (int j = 0; j < 8; ++j) {
                float a = acc[i][j];
                a = __builtin_fmaf(xv[i].x, ev[j].x, a);
                a = __builtin_fmaf(xv[i].y, ev[j].y, a);
                a = __builtin_fmaf(xv[i].z, ev[j].z, a);
                a = __builtin_fmaf(xv[i].w, ev[j].w, a);
                acc[i][j] = a;
            }
    }

    // epilogue: dist + per-row argmin over this block's 128 codes
    float Ar[8], Bc[8];
#pragma unroll
    for (int i = 0; i < 8; ++i) Ar[i] = An[n0 + ty + 16 * i];
#pragma unroll
    for (int j = 0; j < 8; ++j) Bc[j] = Bn[cg * 128 + tx + 16 * j];

    const size_t base = (size_t)blockIdx.x * 128;
#pragma unroll
    for (int i = 0; i < 8; ++i) {
        unsigned long long best = ~0ULL;
#pragma unroll
        for (int j = 0; j < 8; ++j) {
            float s = Ar[i] + Bc[j];                 // fl(A+B)
            float dist = s - 2.0f * acc[i][j];       // fl(s - 2C) (2C exact)
            unsigned long long key = ((unsigned long long)fsort(dist) << 32)
                                   | (unsigned)(cg * 128 + tx + 16 * j);
            best = (key < best) ? key : best;
        }
        // reduce across the 16 tx lanes sharing this row (lane bits 0..3)
#pragma unroll
        for (int m = 1; m < 16; m <<= 1) {
            unsigned long long o = __shfl_xor(best, m, 64);
            best = (o < best) ? o : best;
        }
        if (tx == 0) cand[base + ty + 16 * i] = best;
    }
}

// ---------------------------------------------------------------------------
// Kernel 3: merge candidates -> idx; write z_st (= z + fl(z_q - z)); counts;
// fp64 loss partial sum.
// ---------------------------------------------------------------------------
__global__ void merge_kernel(const float* __restrict__ z_e,
                             const float* __restrict__ emb,
                             const unsigned long long* __restrict__ cand,
                             float* __restrict__ out0,
                             uint32_t* __restrict__ idx,
                             uint32_t* __restrict__ counts,
                             double* __restrict__ loss_sum) {
    int n = blockIdx.x * blockDim.x + threadIdx.x;   // 128 blocks * 256
    int rg = n >> 7, r = n & 127;
    unsigned long long best = ~0ULL;
#pragma unroll
    for (int cg = 0; cg < 8; ++cg) {
        unsigned long long k = cand[((size_t)rg * 8 + cg) * 128 + r];
        best = (k < best) ? k : best;
    }
    uint32_t code = (uint32_t)best;
    idx[n] = code;
    atomicAdd(&counts[code], 1u);

    int b = n >> 10, hw = n & 1023;
    const float* zp = z_e + (size_t)b * 65536 + hw;
    float*       op = out0 + (size_t)b * 65536 + hw;
    const float* ep = emb + (size_t)code * 64;
    double ls = 0.0;
#pragma unroll
    for (int d = 0; d < 64; ++d) {
        float z  = zp[(size_t)d * 1024];
        float zq = ep[d];
        float t  = zq - z;               // fl(z_q - z), as in np
        op[(size_t)d * 1024] = z + t;    // straight-through value
        ls += (double)t * (double)t;
    }
#pragma unroll
    for (int m = 32; m >= 1; m >>= 1) ls += __shfl_down(ls, m, 64);
    if ((threadIdx.x & 63) == 0) atomicAdd(loss_sum, ls);
}

// ---------------------------------------------------------------------------
// Kernel 4: scalars (loss, perplexity) in fp64 (2% thresholds, big slack)
// ---------------------------------------------------------------------------
__global__ void scalar_kernel(const uint32_t* __restrict__ counts,
                              const double* __restrict__ loss_sum,
                              float* __restrict__ out) {
    __shared__ double red[4];
    int t = threadIdx.x;   // 256
    double h = 0.0;
    for (int i = t; i < Kk; i += 256) {
        double p = (double)counts[i] * (1.0 / 32768.0);
        h += p * log(p + 1e-10);
    }
#pragma unroll
    for (int m = 32; m >= 1; m >>= 1) h += __shfl_down(h, m, 64);
    if ((t & 63) == 0) red[t >> 6] = h;
    __syncthreads();
    if (t == 0) {
        double H = red[0] + red[1] + red[2] + red[3];
        out[OUT_PERP] = (float)exp(-H);
        float m32 = (float)(loss_sum[0] * (1.0 / 2097152.0));
        out[OUT_LOSS] = m32 + 0.25f * m32;   // q + 0.25*e, q==e numerically
    }
}

// ---------------------------------------------------------------------------
// Kernel 5: one-hot encodings, float4 stores (writes the whole 134MB region,
// including the candidate scratch at its tail — consumed already).
// ---------------------------------------------------------------------------
__global__ void enc_kernel(const uint32_t* __restrict__ idx,
                           float* __restrict__ enc) {
    int t = threadIdx.x;     // 256; grid 8192
#pragma unroll
    for (int i = 0; i < 4; ++i) {
        int row = blockIdx.x + i * 8192;
        uint32_t code = idx[row];
        float4 v;
        uint32_t c0 = (uint32_t)(t * 4);
        v.x = (code == c0 + 0u) ? 1.0f : 0.0f;
        v.y = (code == c0 + 1u) ? 1.0f : 0.0f;
        v.z = (code == c0 + 2u) ? 1.0f : 0.0f;
        v.w = (code == c0 + 3u) ? 1.0f : 0.0f;
        ((float4*)enc)[(size_t)row * 256 + t] = v;
    }
}

extern "C" void kernel_launch(void* const* d_in, const int* in_sizes, int n_in,
                              void* d_out, int out_size, void* d_ws, size_t ws_size,
                              hipStream_t stream) {
    const float* z_e = (const float*)d_in[0];
    const float* emb = (const float*)d_in[1];
    float* out = (float*)d_out;
    char* ws = (char*)d_ws;

    double*   loss_sum = (double*)(ws + WS_LOSS);
    uint32_t* counts   = (uint32_t*)(ws + WS_CNT);
    float*    Bn       = (float*)(ws + WS_BN);
    float*    An       = (float*)(ws + WS_AN);
    uint32_t* idx      = (uint32_t*)(ws + WS_IDX);
    unsigned long long* cand = (unsigned long long*)(out + CAND_FLOAT_OFF);

    // zero loss accumulator + counts (ws is poisoned 0xAA before every call)
    hipMemsetAsync(ws, 0, WS_CNT + 4096, stream);

    norms_kernel<<<(Nn + Kk) / 256, 256, 0, stream>>>(z_e, emb, An, Bn);
    dist_kernel<<<2048, 256, 0, stream>>>(z_e, emb, An, Bn, cand);
    merge_kernel<<<Nn / 256, 256, 0, stream>>>(z_e, emb, cand, out, idx, counts, loss_sum);
    scalar_kernel<<<1, 256, 0, stream>>>(counts, loss_sum, out);
    enc_kernel<<<8192, 256, 0, stream>>>(idx, out + OUT_ENC);
}